// Round 1
// baseline (325.760 us; speedup 1.0000x reference)
//
#include <hip/hip_runtime.h>
#include <hip/hip_bf16.h>
#include <stdint.h>

#define IN_F   4096
#define OUT_F  4096
#define M_ROWS 2048
#define LORA_SCALE 2.0f   // 32.0 / 16

typedef __bf16 bf16x8 __attribute__((ext_vector_type(8)));
typedef float  f32x4  __attribute__((ext_vector_type(4)));

typedef const __attribute__((address_space(1))) void gvoid_t;
typedef __attribute__((address_space(3))) void lvoid_t;

// ---------- 1. dequant: packed 4-bit (one byte per int32) -> bf16 W[OUT_F][IN_F]
__global__ void dequant_kernel(const int* __restrict__ qw,
                               const float* __restrict__ scales,
                               __hip_bfloat16* __restrict__ W) {
    int t = blockIdx.x * 256 + threadIdx.x;     // 4 packed bytes -> 8 weights
    int4 q = ((const int4*)qw)[t];
    float scale = scales[t >> 3];               // 32 packed bytes per 64-weight block
    float step = scale * (2.0f / 15.0f);
    int b[4] = {q.x, q.y, q.z, q.w};
    union { __hip_bfloat16 h[8]; uint4 v; } o;
    #pragma unroll
    for (int j = 0; j < 4; ++j) {
        float lo = (float)(b[j] & 15)        * step - scale;
        float hi = (float)((b[j] >> 4) & 15) * step - scale;
        o.h[2*j]   = __float2bfloat16(lo);
        o.h[2*j+1] = __float2bfloat16(hi);
    }
    ((uint4*)W)[t] = o.v;
}

// ---------- 2. x fp32 -> bf16
__global__ void xcast_kernel(const float* __restrict__ x,
                             __hip_bfloat16* __restrict__ xb) {
    int t = blockIdx.x * 256 + threadIdx.x;     // 8 floats per thread
    float4 a = ((const float4*)x)[2*t];
    float4 b = ((const float4*)x)[2*t + 1];
    union { __hip_bfloat16 h[8]; uint4 v; } o;
    o.h[0] = __float2bfloat16(a.x); o.h[1] = __float2bfloat16(a.y);
    o.h[2] = __float2bfloat16(a.z); o.h[3] = __float2bfloat16(a.w);
    o.h[4] = __float2bfloat16(b.x); o.h[5] = __float2bfloat16(b.y);
    o.h[6] = __float2bfloat16(b.z); o.h[7] = __float2bfloat16(b.w);
    ((uint4*)xb)[t] = o.v;
}

// ---------- 3. t[m][r] = sum_k x[m][k] * A[r][k]   (fp32 exact)
__global__ void lora_t_kernel(const float* __restrict__ x,
                              const float* __restrict__ A,
                              float* __restrict__ tout) {
    __shared__ float red[16 * 4 * 16];          // [g][row][r]
    int m0 = blockIdx.x * 4;
    int r = threadIdx.x & 15;
    int g = threadIdx.x >> 4;
    float acc[4] = {0.f, 0.f, 0.f, 0.f};
    for (int kb = 0; kb < 64; ++kb) {
        int k = kb * 64 + g * 4;
        float4 av = *(const float4*)(A + (size_t)r * IN_F + k);
        #pragma unroll
        for (int row = 0; row < 4; ++row) {
            float4 xv = *(const float4*)(x + (size_t)(m0 + row) * IN_F + k);
            acc[row] += xv.x*av.x + xv.y*av.y + xv.z*av.z + xv.w*av.w;
        }
    }
    #pragma unroll
    for (int row = 0; row < 4; ++row) red[g*64 + row*16 + r] = acc[row];
    __syncthreads();
    if (threadIdx.x < 64) {
        int row = threadIdx.x >> 4, rr = threadIdx.x & 15;
        float s = 0.f;
        #pragma unroll
        for (int gg = 0; gg < 16; ++gg) s += red[gg*64 + row*16 + rr];
        tout[(size_t)(m0 + row) * 16 + rr] = s;
    }
}

// ---------- 4. GEMM: out[m][n] = sum_k Xb[m][k]*W[n][k] + bias[n] + 2*dot(t[m],loraB[n])
__global__ __launch_bounds__(256) void gemm_kernel(
        const __hip_bfloat16* __restrict__ A,     // [M, K] bf16
        const __hip_bfloat16* __restrict__ B,     // [N, K] bf16 (= W)
        const float* __restrict__ bias,           // [N]
        const float* __restrict__ loraB,          // [N, 16]
        const float* __restrict__ tmat,           // [M, 16]
        float* __restrict__ out) {                // [M, N]
    const int K = IN_F, N = OUT_F;
    __shared__ union alignas(16) {
        struct { __hip_bfloat16 As[128*32]; __hip_bfloat16 Bs[128*32]; } s;
        float tstage[128 * 16];
    } sm;

    int tid  = threadIdx.x;
    int wave = tid >> 6, lane = tid & 63;
    int wm = wave >> 1, wn = wave & 1;
    int row16 = lane & 15, quad = lane >> 4;
    int m0 = blockIdx.y * 128, n0 = blockIdx.x * 128;

    int srow = lane >> 2;          // 0..15 within 16-row segment
    int scol = (lane & 3) * 8;     // 0,8,16,24

    f32x4 acc[4][4];
    #pragma unroll
    for (int i = 0; i < 4; ++i)
        #pragma unroll
        for (int j = 0; j < 4; ++j) acc[i][j] = (f32x4){0.f, 0.f, 0.f, 0.f};

    const __hip_bfloat16* Abase = A + (size_t)m0 * K;
    const __hip_bfloat16* Bbase = B + (size_t)n0 * K;

    for (int k0 = 0; k0 < K; k0 += 32) {
        #pragma unroll
        for (int j = 0; j < 2; ++j) {
            int seg = wave * 2 + j;                       // 0..7, wave-uniform
            const __hip_bfloat16* gA = Abase + (size_t)(seg*16 + srow) * K + k0 + scol;
            __builtin_amdgcn_global_load_lds((gvoid_t*)gA,
                (lvoid_t*)&sm.s.As[seg * 512], 16, 0, 0);
            const __hip_bfloat16* gB = Bbase + (size_t)(seg*16 + srow) * K + k0 + scol;
            __builtin_amdgcn_global_load_lds((gvoid_t*)gB,
                (lvoid_t*)&sm.s.Bs[seg * 512], 16, 0, 0);
        }
        __syncthreads();

        bf16x8 af[4], bfr[4];
        #pragma unroll
        for (int mt = 0; mt < 4; ++mt)
            af[mt] = *(const bf16x8*)&sm.s.As[(wm*64 + mt*16 + row16)*32 + quad*8];
        #pragma unroll
        for (int nt = 0; nt < 4; ++nt)
            bfr[nt] = *(const bf16x8*)&sm.s.Bs[(wn*64 + nt*16 + row16)*32 + quad*8];
        #pragma unroll
        for (int mt = 0; mt < 4; ++mt)
            #pragma unroll
            for (int nt = 0; nt < 4; ++nt)
                acc[mt][nt] = __builtin_amdgcn_mfma_f32_16x16x32_bf16(
                    af[mt], bfr[nt], acc[mt][nt], 0, 0, 0);
        __syncthreads();
    }

    // stage t rows for this m-block into (reused) LDS: 128 x 16 fp32
    for (int i = tid; i < 512; i += 256)
        ((float4*)sm.tstage)[i] = ((const float4*)(tmat + (size_t)m0 * 16))[i];
    __syncthreads();

    #pragma unroll
    for (int nt = 0; nt < 4; ++nt) {
        int nl = wn*64 + nt*16 + row16;
        int n  = n0 + nl;
        float bn = bias[n];
        const float4* lb = (const float4*)(loraB + (size_t)n * 16);
        float4 lb0 = lb[0], lb1 = lb[1], lb2 = lb[2], lb3 = lb[3];
        #pragma unroll
        for (int mt = 0; mt < 4; ++mt) {
            #pragma unroll
            for (int r = 0; r < 4; ++r) {
                int ml = wm*64 + mt*16 + quad*4 + r;
                const float* tm = &sm.tstage[ml * 16];
                float dot =
                    tm[0]*lb0.x + tm[1]*lb0.y + tm[2]*lb0.z + tm[3]*lb0.w +
                    tm[4]*lb1.x + tm[5]*lb1.y + tm[6]*lb1.z + tm[7]*lb1.w +
                    tm[8]*lb2.x + tm[9]*lb2.y + tm[10]*lb2.z + tm[11]*lb2.w +
                    tm[12]*lb3.x + tm[13]*lb3.y + tm[14]*lb3.z + tm[15]*lb3.w;
                out[(size_t)(m0 + ml) * N + n] = acc[mt][nt][r] + bn + LORA_SCALE * dot;
            }
        }
    }
}

extern "C" void kernel_launch(void* const* d_in, const int* in_sizes, int n_in,
                              void* d_out, int out_size, void* d_ws, size_t ws_size,
                              hipStream_t stream) {
    const float* x      = (const float*)d_in[0];   // [2,1024,4096]
    const int*   qw     = (const int*)d_in[1];     // [8388608] one byte each
    const float* scales = (const float*)d_in[2];   // [262144]
    const float* bias   = (const float*)d_in[3];   // [4096]
    const float* loraA  = (const float*)d_in[4];   // [16,4096]
    const float* loraB  = (const float*)d_in[5];   // [4096,16]
    float* out = (float*)d_out;

    char* ws = (char*)d_ws;
    __hip_bfloat16* Wb = (__hip_bfloat16*)ws;                           // 33,554,432 B
    __hip_bfloat16* Xb = (__hip_bfloat16*)(ws + 33554432);              // 16,777,216 B
    float* tmat        = (float*)(ws + 33554432 + 16777216);            //    131,072 B

    dequant_kernel<<<8192, 256, 0, stream>>>(qw, scales, Wb);
    xcast_kernel  <<<4096, 256, 0, stream>>>(x, Xb);
    lora_t_kernel <<<512,  256, 0, stream>>>(x, loraA, tmat);
    gemm_kernel   <<<dim3(32, 16), 256, 0, stream>>>(Xb, Wb, bias, loraB, tmat, out);
}